// Round 4
// baseline (4765.253 us; speedup 1.0000x reference)
//
#include <hip/hip_runtime.h>

// Pool_FPS: furthest point sampling (B=8, N=32768, K=1024) + gather (C=128).
// FPS kernel: 1 block per batch, 1024 threads, 32 pts/thread (interleaved).
//
// ROUND-3 LESSON: __launch_bounds__' 2nd arg behaved as min-BLOCKS-per-CU
// (CUDA semantics): (512,2)->128-reg cap, (1024,4)->64-reg cap -> scratch
// spill of the 96-float per-thread state -> 4.6us/iter (L2-resident scratch,
// invisible in FETCH_SIZE). This round: pin occupancy explicitly with
// amdgpu_waves_per_eu(4,4) (+ flat_work_group_size) -> VGPR budget 512/4=128,
// which fits xs+ys+ds (96) + ~12 temps with ZERO spill. z in dynamic LDS
// (128KB); centers in SGPRs (readfirstlane + scalar loads, L2-resident).
//
//  - exact fp32 arithmetic matching numpy/jax: d = ((dx*dx + dy*dy) + dz*dz),
//    rn ops, no fma contraction; argmax tie-break = smallest index.
//  - one barrier per iteration: wave argmax -> LDS slots (parity-buffered)
//    -> syncthreads -> all threads redundantly reduce 16 wave slots.
// Gather kernel: one thread per output element.

#define BATCH 8
#define NPTS 32768
#define KSEL 1024
#define CFEAT 128
#define TPB 1024
#define PT (NPTS / TPB)   // 32 points per thread
#define NWAVE (TPB / 64)  // 16 waves

__global__ void
__attribute__((amdgpu_flat_work_group_size(TPB, TPB), amdgpu_waves_per_eu(4, 4)))
fps_kernel(const float* __restrict__ xyz, int* __restrict__ idxbuf) {
    extern __shared__ float smem[];
    float* zsh = smem;                       // [NPTS] 128KB
    float* sd  = smem + NPTS;                // [2][NWAVE] parity-buffered wave maxima
    int*   sn  = (int*)(smem + NPTS + 2 * NWAVE);  // [2][NWAVE]

    const int b   = blockIdx.x;
    const int tid = threadIdx.x;
    const float* Xp = xyz + (size_t)b * 3 * NPTS;
    const float* Yp = Xp + NPTS;
    const float* Zp = Xp + 2 * NPTS;

    float xs[PT], ys[PT], ds[PT];
#pragma unroll
    for (int j = 0; j < PT; ++j) {
        const int n = tid + j * TPB;         // interleaved: coalesced global loads,
        xs[j] = Xp[n];                       // LDS stride 4B -> 2-way (free)
        ys[j] = Yp[n];
        zsh[n] = Zp[n];
        ds[j] = __builtin_inff();
    }
    if (tid == 0) idxbuf[(size_t)b * KSEL] = 0;  // idx[0] = 0
    float cx = Xp[0], cy = Yp[0], cz = Zp[0];
    __syncthreads();

    const int lane = tid & 63;
    const int wid  = tid >> 6;

    for (int t = 1; t < KSEL; ++t) {
        float bd = -__builtin_inff();
        int   bj = 0;
#pragma unroll
        for (int j = 0; j < PT; ++j) {
            const int n = tid + j * TPB;
            const float dx = xs[j] - cx;
            const float dy = ys[j] - cy;
            const float dz = zsh[n] - cz;
            // exact: ((dx*dx + dy*dy) + dz*dz), rn, no fma contraction
            const float d = __fadd_rn(__fadd_rn(__fmul_rn(dx, dx), __fmul_rn(dy, dy)),
                                      __fmul_rn(dz, dz));
            const float nd = fminf(ds[j], d);
            ds[j] = nd;
            // strict > keeps smallest j (=> smallest n for this thread)
            const bool gt = nd > bd;
            bd = gt ? nd : bd;
            bj = gt ? j : bj;
        }
        int bn = tid + bj * TPB;
        // wave argmax: max d, tie -> min index
#pragma unroll
        for (int off = 32; off >= 1; off >>= 1) {
            const float od = __shfl_xor(bd, off);
            const int   on = __shfl_xor(bn, off);
            if (od > bd || (od == bd && on < bn)) { bd = od; bn = on; }
        }
        const int p = (t & 1) * NWAVE;
        if (lane == 0) { sd[p + wid] = bd; sn[p + wid] = bn; }
        __syncthreads();
        // all threads redundantly reduce the NWAVE wave results (broadcast reads)
        float rd = sd[p];
        int   rn = sn[p];
#pragma unroll
        for (int w = 1; w < NWAVE; ++w) {
            const float od = sd[p + w];
            const int   on = sn[p + w];
            if (od > rd || (od == rd && on < rn)) { rd = od; rn = on; }
        }
        const int rns = __builtin_amdgcn_readfirstlane(rn);
        if (tid == 0) idxbuf[(size_t)b * KSEL + t] = rns;
        // scalar (SGPR) center fetch, L2-resident
        cx = Xp[rns]; cy = Yp[rns]; cz = Zp[rns];
    }
}

__global__ void gather_kernel(const float* __restrict__ xyz,
                              const float* __restrict__ feat,
                              const int* __restrict__ idxbuf,
                              float* __restrict__ out) {
    const int SN = BATCH * 3 * KSEL;                  // 24576
    const int total = SN + BATCH * CFEAT * KSEL;      // 1073152
    const int i = blockIdx.x * blockDim.x + threadIdx.x;
    if (i >= total) return;
    if (i < SN) {
        const int b = i / (3 * KSEL);
        const int r = i - b * 3 * KSEL;
        const int c = r / KSEL;
        const int k = r - c * KSEL;
        const int n = idxbuf[b * KSEL + k];
        out[i] = xyz[((size_t)b * 3 + c) * NPTS + n];
    } else {
        const int i2 = i - SN;
        const int b = i2 / (CFEAT * KSEL);
        const int r = i2 - b * CFEAT * KSEL;
        const int c = r / KSEL;
        const int k = r - c * KSEL;
        const int n = idxbuf[b * KSEL + k];
        out[SN + i2] = feat[((size_t)b * CFEAT + c) * NPTS + n];
    }
}

extern "C" void kernel_launch(void* const* d_in, const int* in_sizes, int n_in,
                              void* d_out, int out_size, void* d_ws, size_t ws_size,
                              hipStream_t stream) {
    const float* xyz  = (const float*)d_in[0];
    const float* feat = (const float*)d_in[1];
    float* out = (float*)d_out;
    int* idxbuf = (int*)d_ws;  // BATCH*KSEL ints = 32KB

    const size_t smem_bytes = (size_t)(NPTS + 4 * NWAVE) * sizeof(float);  // ~128.3KB
    hipFuncSetAttribute((const void*)fps_kernel,
                        hipFuncAttributeMaxDynamicSharedMemorySize, (int)smem_bytes);

    fps_kernel<<<BATCH, TPB, smem_bytes, stream>>>(xyz, idxbuf);

    const int total = BATCH * 3 * KSEL + BATCH * CFEAT * KSEL;  // 1073152
    gather_kernel<<<(total + 255) / 256, 256, 0, stream>>>(xyz, feat, idxbuf, out);
}